// Round 7
// baseline (230.237 us; speedup 1.0000x reference)
//
#include <hip/hip_runtime.h>

// B=4, C=256, H=W=64 (N=4096). QKV 1x1conv -> spatial attention (softmax over
// j only => independent per-64-key-chunk softmax) -> channel LayerNorm.
// f16 MFMA 32x32x16, fp32 accumulation.
//
// R7: prep fused into gemm -> single qkv kernel (768 blocks, 2/CU). x-tile is
// transpose-staged [c][p]fp32 -> [p][c]f16 in LDS (coalesced 256B row reads);
// weight quarters cvt8-staged from L2-resident fp32. Kills X1T/X2T round-trip
// (33MB) and one kernel boundary. attn identical to R6 (two wave-groups).

#define CDIM 256
#define NPOS 4096
#define BATCH 4
#define EPSV 1e-5f

typedef _Float16 f16;
typedef __attribute__((ext_vector_type(8))) _Float16 f16x8;
typedef __attribute__((ext_vector_type(4))) float f32x4;
typedef __attribute__((ext_vector_type(16))) float f32x16;

#define WST       264   // f16; 528B = 33*16 -> b128-aligned rows
#define QK_STRIDE 264
#define S_STRIDE  68    // f32; 272B = 17*16
#define P_STRIDE  72
#define DQ_STRIDE 72
#define FT_STRIDE 66    // f32 merge buffer; 2-way only

// MFMA 32x32x16 f16:
//   A: lane l holds A[m=l&31][k=(l>>5)*8+j]
//   B: lane l holds B[k=(l>>5)*8+j][n=l&31]
//   C/D: lane l, reg r -> col=l&31, row=(r&3)+8*(r>>2)+4*(l>>5)

static __device__ __forceinline__ f16x8 cvt8(const float* __restrict__ p) {
    float4 w0 = *(const float4*)p;
    float4 w1 = *(const float4*)(p + 4);
    f16x8 r;
    r[0] = (f16)w0.x; r[1] = (f16)w0.y; r[2] = (f16)w0.z; r[3] = (f16)w0.w;
    r[4] = (f16)w1.x; r[5] = (f16)w1.y; r[6] = (f16)w1.z; r[7] = (f16)w1.w;
    return r;
}

// ---------------------------------------------------------------------------
// qkv: grid 768 = proj(3) x b(4) x ptile(64). Per block: 64 positions x 256
// outputs. x tile [256c][64p] fp32 transpose-staged to Xs [p][c] f16 in LDS;
// weight quarters (64 o-rows) cvt8-staged to Wh. All MFMA operands from LDS;
// split-k dual acc; LDS-assisted coalesced stores. LDS ~78 KB -> 2 blocks/CU.
// Q,K -> [B][N][C] f16; V -> [B][C][N] f16.
// ---------------------------------------------------------------------------
__global__ __launch_bounds__(256, 2) void qkv_kernel(
    const float* __restrict__ x1, const float* __restrict__ x2,
    const float* __restrict__ qw, const float* __restrict__ kw,
    const float* __restrict__ vw,
    const float* __restrict__ qb, const float* __restrict__ kb,
    const float* __restrict__ vb,
    f16* __restrict__ Qg, f16* __restrict__ Kg, f16* __restrict__ Vg)
{
    __shared__ f16 Xs[64 * WST];         // 33792 B  [p][c]
    __shared__ f16 Wh[64 * WST];         // 33792 B  weight quarter [o_l][c]
    __shared__ f16 Ds[64 * DQ_STRIDE];   //  9216 B  output quarter staging
    __shared__ float biasS[256];

    const int id = blockIdx.x;
    const int pr  = id >> 8;             // 0=Q 1=K 2=V
    const int rem = id & 255;
    const int b   = rem >> 6;
    const int p0  = (rem & 63) << 6;
    const float* xs   = (pr == 0) ? x1 : x2;
    const float* Wp   = pr == 0 ? qw : pr == 1 ? kw : vw;
    const float* bias = pr == 0 ? qb : pr == 1 ? kb : vb;

    const int t = threadIdx.x, w = t >> 6, l = t & 63, lm = l & 31, lh = l >> 5;
    const int pt = w & 1, ot = w >> 1;   // wave tile within 64p x 64o quarter

    biasS[t] = bias[t];

    // transpose-stage x tile: [c][p] fp32 global -> [p][c] f16 LDS.
    // lane p = t&63 (coalesced 256B per c-row), c-pairs per thread-group.
    {
        const int p  = t & 63;
        const int cg = (t >> 6) * 2;
        const float* src = xs + (size_t)b * CDIM * NPOS + p0 + p;
        #pragma unroll
        for (int c = cg; c < CDIM; c += 8) {
            float a0 = src[(size_t)c * NPOS];
            float a1 = src[(size_t)(c + 1) * NPOS];
            Xs[p * WST + c]     = (f16)a0;
            Xs[p * WST + c + 1] = (f16)a1;
        }
    }

    for (int q = 0; q < 4; ++q) {
        // stage weight quarter [64][256] fp32 -> f16, coalesced
        #pragma unroll
        for (int i = 0; i < 8; ++i) {
            int g = t + i * 256;
            int row = g >> 5, col = (g & 31) * 8;
            *(f16x8*)&Wh[row * WST + col] = cvt8(Wp + (size_t)(q * 64 + row) * CDIM + col);
        }
        __syncthreads();   // Wh (and, first iter, Xs) ready; Ds free for rewrite

        // 32x32 tile per wave; split-k dual acc to break the dep chain
        f32x16 accA = {}, accB = {};
        #pragma unroll
        for (int ks = 0; ks < 16; ks += 2) {
            f16x8 x0 = *(const f16x8*)&Xs[(pt * 32 + lm) * WST + ks * 16 + lh * 8];
            f16x8 w0 = *(const f16x8*)&Wh[(ot * 32 + lm) * WST + ks * 16 + lh * 8];
            f16x8 x1v = *(const f16x8*)&Xs[(pt * 32 + lm) * WST + (ks + 1) * 16 + lh * 8];
            f16x8 w1 = *(const f16x8*)&Wh[(ot * 32 + lm) * WST + (ks + 1) * 16 + lh * 8];
            if (pr < 2) {
                accA = __builtin_amdgcn_mfma_f32_32x32x16_f16(x0, w0, accA, 0, 0, 0);
                accB = __builtin_amdgcn_mfma_f32_32x32x16_f16(x1v, w1, accB, 0, 0, 0);
            } else {
                accA = __builtin_amdgcn_mfma_f32_32x32x16_f16(w0, x0, accA, 0, 0, 0);
                accB = __builtin_amdgcn_mfma_f32_32x32x16_f16(w1, x1v, accB, 0, 0, 0);
            }
        }

        // stage output quarter into Ds
        if (pr < 2) {
            int o_l = ot * 32 + lm;
            float bv = biasS[q * 64 + o_l];
            #pragma unroll
            for (int r = 0; r < 16; ++r) {
                int p_l = pt * 32 + (r & 3) + 8 * (r >> 2) + 4 * lh;
                Ds[p_l * DQ_STRIDE + o_l] = (f16)(accA[r] + accB[r] + bv);
            }
        } else {
            #pragma unroll
            for (int r = 0; r < 16; ++r) {
                int o_l = ot * 32 + (r & 3) + 8 * (r >> 2) + 4 * lh;
                Ds[o_l * DQ_STRIDE + pt * 32 + lm] =
                    (f16)(accA[r] + accB[r] + biasS[q * 64 + o_l]);
            }
        }
        __syncthreads();   // Ds ready

        // coalesced quarter store: 64 rows x 64 cols f16 = 512 f16x8
        #pragma unroll
        for (int j = 0; j < 2; ++j) {
            int row = (t >> 3) + j * 32;
            int cc  = (t & 7) * 8;
            f16x8 vdat = *(const f16x8*)&Ds[row * DQ_STRIDE + cc];
            if (pr < 2) {
                f16* Out = (pr == 0) ? Qg : Kg;
                *(f16x8*)(Out + ((size_t)(b * NPOS + p0 + row)) * CDIM + q * 64 + cc) = vdat;
            } else {
                *(f16x8*)(Vg + ((size_t)(b * CDIM + q * 64 + row)) * NPOS + p0 + cc) = vdat;
            }
        }
    }
}

// ---------------------------------------------------------------------------
// attn: identical to R6. grid 256 = (b<<6 | qtile), 512 thr = 2 wave-groups,
// private Ks/Ss/Ps per group, shared barriers; group-1 facc merged via LDS.
// ---------------------------------------------------------------------------
__global__ __launch_bounds__(512, 1) void attn_kernel(
    const f16* __restrict__ Qg, const f16* __restrict__ Kg, const f16* __restrict__ Vg,
    const float* __restrict__ ln_w, const float* __restrict__ ln_b,
    float* __restrict__ out)
{
    __shared__ f16   Ks[2][64 * QK_STRIDE];   // 67584 B (also aliased as Ftmp)
    __shared__ float Ss[2][64 * S_STRIDE];    // 34816 B
    __shared__ f16   Ps[2][64 * P_STRIDE];    // 18432 B
    __shared__ float lnw_s[256], lnb_s[256];
    __shared__ float redS[4 * 64], redQ[4 * 64], mu_s[64], rs_s[64];

    const int t   = threadIdx.x;
    const int b   = blockIdx.x >> 6;
    const int p0  = (blockIdx.x & 63) << 6;
    const int w   = t >> 6;
    const int g   = t >> 8;
    const int wl  = w & 3;
    const int tl  = t & 255;
    const int l   = t & 63;
    const int lm  = l & 31;
    const int lh  = l >> 5;

    if (t < 256) { lnw_s[t] = ln_w[t]; lnb_s[t] = ln_b[t]; }

    const int spt = wl & 1;
    const int skt = wl >> 1;

    f16x8 qf[16];
    {
        const f16* qptr = Qg + (size_t)(b * NPOS + p0 + spt * 32 + lm) * CDIM + lh * 8;
        #pragma unroll
        for (int ks = 0; ks < 16; ++ks) qf[ks] = *(const f16x8*)(qptr + ks * 16);
    }

    const int kr = tl >> 5, koff = (tl & 31) * 8;
    f16x8 kreg[8];
    auto issue_k = [&](int ch) {
        const int i0 = ch * 64;
        #pragma unroll
        for (int r = 0; r < 8; ++r)
            kreg[r] = *(const f16x8*)(Kg + (size_t)(b * NPOS + i0 + r * 8 + kr) * CDIM + koff);
    };
    issue_k(g);

    const f16* vbase0 = Vg + (size_t)(b * CDIM + wl * 64 + lm) * NPOS;
    const f16* vbase1 = Vg + (size_t)(b * CDIM + wl * 64 + 32 + lm) * NPOS;

    f32x16 facc[4] = {};

    for (int it = 0; it < 32; ++it) {
        const int ch = it * 2 + g;
        const int i0 = ch * 64;

        #pragma unroll
        for (int r = 0; r < 8; ++r)
            *(f16x8*)&Ks[g][(r * 8 + kr) * QK_STRIDE + koff] = kreg[r];
        __syncthreads();   // A

        f16x8 vf0[4], vf1[4];
        #pragma unroll
        for (int ks = 0; ks < 4; ++ks) {
            vf0[ks] = *(const f16x8*)(vbase0 + i0 + ks * 16 + lh * 8);
            vf1[ks] = *(const f16x8*)(vbase1 + i0 + ks * 16 + lh * 8);
        }

        f32x16 sacc = {};
        #pragma unroll
        for (int ks = 0; ks < 16; ++ks) {
            f16x8 bb = *(const f16x8*)&Ks[g][(skt * 32 + lm) * QK_STRIDE + ks * 16 + lh * 8];
            sacc = __builtin_amdgcn_mfma_f32_32x32x16_f16(qf[ks], bb, sacc, 0, 0, 0);
        }
        #pragma unroll
        for (int r = 0; r < 16; ++r) {
            int row = (r & 3) + 8 * (r >> 2) + 4 * lh;
            Ss[g][(spt * 32 + row) * S_STRIDE + skt * 32 + lm] = sacc[r];
        }
        __syncthreads();   // B

        {
            const int r  = tl >> 2;
            const int sg = (tl & 3) * 16;
            const float* srow = &Ss[g][r * S_STRIDE + sg];
            float v[16];
            f32x4 a0 = *(const f32x4*)(srow);
            f32x4 a1 = *(const f32x4*)(srow + 4);
            f32x4 a2 = *(const f32x4*)(srow + 8);
            f32x4 a3 = *(const f32x4*)(srow + 12);
            v[0]=a0[0]; v[1]=a0[1]; v[2]=a0[2]; v[3]=a0[3];
            v[4]=a1[0]; v[5]=a1[1]; v[6]=a1[2]; v[7]=a1[3];
            v[8]=a2[0]; v[9]=a2[1]; v[10]=a2[2]; v[11]=a2[3];
            v[12]=a3[0]; v[13]=a3[1]; v[14]=a3[2]; v[15]=a3[3];
            float m = v[0];
            #pragma unroll
            for (int i = 1; i < 16; ++i) m = fmaxf(m, v[i]);
            m = fmaxf(m, __shfl_xor(m, 1));
            m = fmaxf(m, __shfl_xor(m, 2));
            float s = 0.f;
            #pragma unroll
            for (int i = 0; i < 16; ++i) { float e = __expf(v[i] - m); v[i] = e; s += e; }
            s += __shfl_xor(s, 1);
            s += __shfl_xor(s, 2);
            float inv = __builtin_amdgcn_rcpf(s);
            f16x8 h0, h1;
            #pragma unroll
            for (int i = 0; i < 8; ++i) { h0[i] = (f16)(v[i] * inv); h1[i] = (f16)(v[i + 8] * inv); }
            *(f16x8*)&Ps[g][r * P_STRIDE + sg]     = h0;
            *(f16x8*)&Ps[g][r * P_STRIDE + sg + 8] = h1;
        }
        __syncthreads();   // C

        if (it < 31) issue_k(ch + 2);

        #pragma unroll
        for (int ks = 0; ks < 4; ++ks) {
            f16x8 bp0 = *(const f16x8*)&Ps[g][lm * P_STRIDE + ks * 16 + lh * 8];
            f16x8 bp1 = *(const f16x8*)&Ps[g][(32 + lm) * P_STRIDE + ks * 16 + lh * 8];
            facc[0] = __builtin_amdgcn_mfma_f32_32x32x16_f16(vf0[ks], bp0, facc[0], 0, 0, 0);
            facc[1] = __builtin_amdgcn_mfma_f32_32x32x16_f16(vf0[ks], bp1, facc[1], 0, 0, 0);
            facc[2] = __builtin_amdgcn_mfma_f32_32x32x16_f16(vf1[ks], bp0, facc[2], 0, 0, 0);
            facc[3] = __builtin_amdgcn_mfma_f32_32x32x16_f16(vf1[ks], bp1, facc[3], 0, 0, 0);
        }
    }

    float* Ftmp = (float*)&Ks[0][0];
    __syncthreads();   // D
    if (g == 1) {
        #pragma unroll
        for (int ii = 0; ii < 2; ++ii)
            #pragma unroll
            for (int jj = 0; jj < 2; ++jj)
                #pragma unroll
                for (int r = 0; r < 16; ++r) {
                    int c = wl * 64 + ii * 32 + (r & 3) + 8 * (r >> 2) + 4 * lh;
                    int p = jj * 32 + lm;
                    Ftmp[c * FT_STRIDE + p] = facc[ii * 2 + jj][r];
                }
    }
    __syncthreads();   // E
    float ps0 = 0.f, ps1 = 0.f, pq0 = 0.f, pq1 = 0.f;
    if (g == 0) {
        #pragma unroll
        for (int ii = 0; ii < 2; ++ii)
            #pragma unroll
            for (int jj = 0; jj < 2; ++jj)
                #pragma unroll
                for (int r = 0; r < 16; ++r) {
                    int c = wl * 64 + ii * 32 + (r & 3) + 8 * (r >> 2) + 4 * lh;
                    int p = jj * 32 + lm;
                    facc[ii * 2 + jj][r] += Ftmp[c * FT_STRIDE + p];
                }
        #pragma unroll
        for (int ii = 0; ii < 2; ++ii) {
            #pragma unroll
            for (int r = 0; r < 16; ++r) {
                float a = facc[ii * 2 + 0][r];
                float c = facc[ii * 2 + 1][r];
                ps0 += a; pq0 += a * a;
                ps1 += c; pq1 += c * c;
            }
        }
        ps0 += __shfl_xor(ps0, 32); pq0 += __shfl_xor(pq0, 32);
        ps1 += __shfl_xor(ps1, 32); pq1 += __shfl_xor(pq1, 32);
        if (lh == 0) {
            redS[wl * 64 + lm] = ps0;        redQ[wl * 64 + lm] = pq0;
            redS[wl * 64 + 32 + lm] = ps1;   redQ[wl * 64 + 32 + lm] = pq1;
        }
    }
    __syncthreads();   // F
    if (t < 64) {
        float s = redS[t] + redS[64 + t] + redS[128 + t] + redS[192 + t];
        float q = redQ[t] + redQ[64 + t] + redQ[128 + t] + redQ[192 + t];
        float mean = s * (1.0f / 256.0f);
        float var  = q * (1.0f / 256.0f) - mean * mean;
        mu_s[t] = mean;
        rs_s[t] = rsqrtf(var + EPSV);
    }
    __syncthreads();   // G
    if (g == 0) {
        #pragma unroll
        for (int ii = 0; ii < 2; ++ii) {
            #pragma unroll
            for (int jj = 0; jj < 2; ++jj) {
                int p = jj * 32 + lm;
                float mu = mu_s[p], rs = rs_s[p];
                float* dst = out + (size_t)b * CDIM * NPOS + p0 + p;
                #pragma unroll
                for (int r = 0; r < 16; ++r) {
                    int c = wl * 64 + ii * 32 + (r & 3) + 8 * (r >> 2) + 4 * lh;
                    float vL = facc[ii * 2 + jj][r];
                    dst[(size_t)c * NPOS] = (vL - mu) * rs * lnw_s[c] + lnb_s[c];
                }
            }
        }
    }
}

// ---------------------------------------------------------------------------
extern "C" void kernel_launch(void* const* d_in, const int* in_sizes, int n_in,
                              void* d_out, int out_size, void* d_ws, size_t ws_size,
                              hipStream_t stream)
{
    const float* x1  = (const float*)d_in[0];
    const float* x2  = (const float*)d_in[1];
    const float* qw  = (const float*)d_in[2];
    const float* qb  = (const float*)d_in[3];
    const float* kw  = (const float*)d_in[4];
    const float* kb  = (const float*)d_in[5];
    const float* vw  = (const float*)d_in[6];
    const float* vb  = (const float*)d_in[7];
    const float* lnw = (const float*)d_in[8];
    const float* lnb = (const float*)d_in[9];

    const size_t tsz = (size_t)BATCH * NPOS * CDIM;
    f16* Qg  = (f16*)d_ws;
    f16* Kg  = Qg + tsz;
    f16* Vg  = Kg + tsz;

    qkv_kernel<<<768, 256, 0, stream>>>(x1, x2, qw, kw, vw, qb, kb, vb, Qg, Kg, Vg);
    attn_kernel<<<256, 512, 0, stream>>>(Qg, Kg, Vg, lnw, lnb, (float*)d_out);
}